// Round 8
// baseline (453.845 us; speedup 1.0000x reference)
//
#include <hip/hip_runtime.h>

// y = x @ W^T + bias. x:[65536,512] f32, W:[512,512] f32, bias:[512] f32.
// R10: 2-blocks/CU desynchronized streaming (TLP fix).
//   Evidence: all 1-block/CU lockstep variants (R2/R3/R7/R9) pin at
//   106-125us moving ~230MB at ~2.05 TB/s effective; R5's continuous
//   streamer sustained ~7 TB/s at cache level but moved 5x the bytes.
//   Fix: keep traffic minimal-ish (X 2x via BN=256) but shrink the block
//   so TWO blocks co-reside per CU and fill each other's memory gaps:
//   BM=128 BN=256 BK=32, 48KB LDS (f32, global_load_lds DMA, single buf),
//   acc[4][4]=64 AGPR, <=128 VGPR (__launch_bounds__(512,4) -> 4 waves/
//   SIMD = 16 waves/CU). Frag reads hoisted to regs so tile t+1's DMA
//   issues before the MFMA burst. setprio(1) around MFMAs (desynced-wave
//   regime, T5). 1024 blocks; n-pair of each m-tile XCD-paired for X L2
//   sharing. Source-side XOR swizzle (R9 mechanics, verified correct).

typedef __bf16 bf16x8 __attribute__((ext_vector_type(8)));
typedef float f32x4 __attribute__((ext_vector_type(4)));
typedef __attribute__((address_space(3))) unsigned int lds_uint;
typedef const __attribute__((address_space(1))) unsigned int gbl_uint;

__global__ __launch_bounds__(512, 4)
void linear_tlp(const float* __restrict__ X, const float* __restrict__ W,
                const float* __restrict__ bias, float* __restrict__ Y) {
  constexpr int K = 512, N = 512;

  // f32 tiles, 128 B rows (32 k-floats). A: 128 rows (16KB), B: 256 (32KB).
  __shared__ float As[128 * 32];
  __shared__ float Bs[256 * 32];

  const int tid  = threadIdx.x;
  const int lane = tid & 63;
  const int wave = tid >> 6;

  // 1024 blocks = 512 m x 2 n; n-sharers of an m-tile differ by 8 -> same
  // XCD under round-robin -> X tile's 2nd read is an L2 hit.
  const int id = blockIdx.x;
  const int m  = ((id >> 4) << 3) | (id & 7);   // 0..511
  const int n  = (id >> 3) & 1;
  const int bm = m << 7;                        // *128
  const int bn = n << 8;                        // *256

  const int wm = (wave >> 2) << 6;  // 0 / 64
  const int wn = (wave & 3) << 6;   // 0..192

  // ---- DMA staging (source-side swizzle; LDS dest linear) ----
  // lane l: row offset r8 = l>>3, LDS slot l&7 (HW lane*16), global k-group
  // (l&7)^r8  [involution with row&7 = r8].
  const int r8 = lane >> 3;
  const int sw = ((lane & 7) ^ r8) * 4;         // float offset of 16B group
  // A: wave w stages rows w*16 + a*8 (a=0,1); B: rows w*32 + a*8 (a=0..3)
  const float* Xsg = X + (size_t)(bm + wave * 16 + r8) * K + sw;
  const float* Wsg = W + (size_t)(bn + wave * 32 + r8) * K + sw;
  char* lAs = (char*)As + wave * 2048;
  char* lBs = (char*)Bs + wave * 4096;

  auto issue_tile = [&](int kt) {
#pragma unroll
    for (int a = 0; a < 2; ++a)
      __builtin_amdgcn_global_load_lds(
          (gbl_uint*)(Xsg + (size_t)a * 8 * K + kt),
          (lds_uint*)(lAs + a * 1024), 16, 0, 0);
#pragma unroll
    for (int a = 0; a < 4; ++a)
      __builtin_amdgcn_global_load_lds(
          (gbl_uint*)(Wsg + (size_t)a * 8 * K + kt),
          (lds_uint*)(lBs + a * 1024), 16, 0, 0);
  };

  // ---- frag-read constants ----
  // frag row = (wm|wn) + f*16 + mrow; k = q*8..+7 -> logical groups 2q,2q+1,
  // physical slot = logical ^ (mrow&7).
  const int mrow = lane & 15;
  const int q    = lane >> 4;
  const int m7   = mrow & 7;
  const int s0   = ((2 * q) ^ m7) << 4;        // byte offsets in row
  const int s1   = ((2 * q + 1) ^ m7) << 4;
  const char* arb = (const char*)As + mrow * 128 + wm * 128;
  const char* brb = (const char*)Bs + mrow * 128 + wn * 128;

  f32x4 acc[4][4] = {};

  issue_tile(0);

#pragma unroll 1
  for (int t = 0; t < 16; ++t) {
    // tile t's 6 DMAs landed
    asm volatile("s_waitcnt vmcnt(0)" ::: "memory");
    __builtin_amdgcn_s_barrier();
    __builtin_amdgcn_sched_barrier(0);

    // hoist ALL frags to regs (f32 -> bf16 cvt on the way)
    bf16x8 af[4], bf[4];
#pragma unroll
    for (int f = 0; f < 4; ++f) {
      f32x4 a0 = *(const f32x4*)(arb + f * 2048 + s0);
      f32x4 a1 = *(const f32x4*)(arb + f * 2048 + s1);
      f32x4 b0 = *(const f32x4*)(brb + f * 2048 + s0);
      f32x4 b1 = *(const f32x4*)(brb + f * 2048 + s1);
      bf16x8 av, bv;
#pragma unroll
      for (int e = 0; e < 4; ++e) {
        av[e] = (__bf16)a0[e];  av[e + 4] = (__bf16)a1[e];
        bv[e] = (__bf16)b0[e];  bv[e + 4] = (__bf16)b1[e];
      }
      af[f] = av;  bf[f] = bv;
    }

    // all LDS reads retired -> safe to overwrite; issue next DMAs so their
    // latency overlaps the MFMA burst (+ the other resident block's work)
    asm volatile("s_waitcnt lgkmcnt(0)" ::: "memory");
    __builtin_amdgcn_s_barrier();
    __builtin_amdgcn_sched_barrier(0);
    if (t < 15) issue_tile((t + 1) * 32);

    __builtin_amdgcn_s_setprio(1);
#pragma unroll
    for (int i2 = 0; i2 < 4; ++i2)
#pragma unroll
      for (int j = 0; j < 4; ++j)
        acc[i2][j] = __builtin_amdgcn_mfma_f32_16x16x32_bf16(af[i2], bf[j],
                                                             acc[i2][j], 0, 0, 0);
    __builtin_amdgcn_s_setprio(0);
  }

  // ---- epilogue: C/D col = lane&15 (n), row = (lane>>4)*4 + r (m) ----
  float bj[4];
#pragma unroll
  for (int j = 0; j < 4; ++j) bj[j] = bias[bn + wn + j * 16 + mrow];
#pragma unroll
  for (int i2 = 0; i2 < 4; ++i2) {
#pragma unroll
    for (int r = 0; r < 4; ++r) {
      const size_t gr = (size_t)(bm + wm + i2 * 16 + q * 4 + r);
      float* yp = Y + gr * N + bn + wn + mrow;
#pragma unroll
      for (int j = 0; j < 4; ++j)
        __builtin_nontemporal_store(acc[i2][j][r] + bj[j], yp + j * 16);
    }
  }
}

extern "C" void kernel_launch(void* const* d_in, const int* in_sizes, int n_in,
                              void* d_out, int out_size, void* d_ws, size_t ws_size,
                              hipStream_t stream) {
  const float* X = (const float*)d_in[0];
  const float* W = (const float*)d_in[1];
  const float* b = (const float*)d_in[2];
  float* Y = (float*)d_out;
  linear_tlp<<<dim3(1024), 512, 0, stream>>>(X, W, b, Y);
}